// Round 10
// baseline (109.838 us; speedup 1.0000x reference)
//
#include <hip/hip_runtime.h>
#include <hip/hip_bf16.h>

// out[b] = 0.1*log1p(1/S_b),  S_b = sum_k exp2(z*H(z) + log2(w_k)), z=(1-ip)/2
// R13: R6's verified dbuf-LDS pipeline with DOUBLED TLP. R12's profile
// explained the fixed gap (43us harness ws-poison fill, unavoidable); main
// remains the lever. R6 ran at only ~9 resident waves/CU (28%); dependent
// 8-deep epilogue chains at 2-3 waves/SIMD match VALUBusy 39%. Fix: halve
// per-block col span (NT=2, 32-col cgs, LDS 2x8KB=16KB), grid 2048 -> 8
// blocks/CU, launch_bounds(256,8) -> up to 32 waves/CU. Two blocks/row-range
// combine via atomicAdd (R11-verified: self memset + fin kernel).
// prep = R12 (fast, verified). Per-lane frag layout unchanged (0 conflicts).

typedef __attribute__((ext_vector_type(8))) short short8;   // 8 bf16
typedef __attribute__((ext_vector_type(4))) float f32x4;
typedef __attribute__((ext_vector_type(2))) float f32x2;

#define KP 1024
#define DD 128

__device__ __forceinline__ unsigned int f2bf(float f) {
  unsigned int u = __float_as_uint(f);
  return (u + 0x7FFFu + ((u >> 16) & 1u)) >> 16;   // RNE fp32->bf16
}

// packed dual-fp32 via vector IR (backend selects v_pk_* with correct mods)
__device__ __forceinline__ f32x2 pk_fma(f32x2 a, f32x2 b, f32x2 c) {
  return __builtin_elementwise_fma(a, b, c);
}

// ---- prep (R12, verified): 64 blocks x 256 thr, 16 cols each.
__global__ __launch_bounds__(256) void prep_kernel(
    const float* __restrict__ mus, const float* __restrict__ alphas,
    uint4* __restrict__ musbf_sw, float* __restrict__ lw) {
  __shared__ float Vt[128][17];     // raw tile, padded
  __shared__ float psum[4][16];
  __shared__ float inv_s[16];
  const int t = threadIdx.x;
  const int wvp = t >> 6, lnp = t & 63;
  const int c0 = blockIdx.x * 16;

  float s = 0.0f;
  #pragma unroll
  for (int j = 0; j < 8; ++j) {
    const int id = j * 256 + t;
    const int d = id >> 4, c = id & 15;
    float v = mus[d * KP + c0 + c];
    Vt[d][c] = v;
    s = fmaf(v, v, s);
  }
  s += __shfl_xor(s, 16, 64);
  s += __shfl_xor(s, 32, 64);
  if (lnp < 16) psum[wvp][lnp] = s;
  __syncthreads();
  if (t < 16) {
    float tot = psum[0][t] + psum[1][t] + psum[2][t] + psum[3][t];
    inv_s[t] = rsqrtf(tot);
    lw[c0 + t] = -14.4269504089f * alphas[c0 + t];  // log2(exp(-10a))
  }
  __syncthreads();

  const int col16 = t & 15, w0 = t >> 4;
  const int col = c0 + col16;
  const float inv = inv_s[col16];
  uint4 o;
  o.x = f2bf(Vt[w0 * 8 + 0][col16] * inv) | (f2bf(Vt[w0 * 8 + 1][col16] * inv) << 16);
  o.y = f2bf(Vt[w0 * 8 + 2][col16] * inv) | (f2bf(Vt[w0 * 8 + 3][col16] * inv) << 16);
  o.z = f2bf(Vt[w0 * 8 + 4][col16] * inv) | (f2bf(Vt[w0 * 8 + 5][col16] * inv) << 16);
  o.w = f2bf(Vt[w0 * 8 + 6][col16] * inv) | (f2bf(Vt[w0 * 8 + 7][col16] * inv) << 16);
  musbf_sw[((col >> 6) << 10) + (w0 << 6) + (col & 63)] = o;
}

// ---- main: 2048 blocks x 256 thr (8 blocks/CU target). Block b:
// rows (b>>1)*64, col-half (b&1) -> 16 cgs of 32 cols (ci = (b&1)*16+cgi).
// Wave wv: rows +wv*16 (A regs). B staged into 2x8KB LDS dbuf with register
// prefetch; each cg: 8 MFMA + packed epilogue. Partials atomicAdd'ed.
// Global 16B-unit index for 32-col group ci, unit u (=w0*32+c32):
//   (ci>>1)*1024 + (u>>5)*64 + (ci&1)*32 + (u&31)
// LDS short offset for frag (kkk,nt,q,l15): kkk*1024+q*256+nt*128+l15*8.
__global__ __launch_bounds__(256, 8) void main_kernel(
    const float* __restrict__ xs, const uint4* __restrict__ musbf_sw,
    const float* __restrict__ lw, float* __restrict__ out) {
  __shared__ __align__(16) unsigned short Bs[2][4096];   // 2 x 8 KB
  const int t = threadIdx.x;
  const int wv = t >> 6, ln = t & 63, q = ln >> 4, l15 = ln & 15;
  const int rblk = blockIdx.x >> 1;          // row-range 0..1023
  const int ch = blockIdx.x & 1;             // col half

  // A fragments: afr[kkk] = xs[row][kkk*32 + q*8 .. +8]
  const int row = rblk * 64 + wv * 16 + l15;
  const float4* xs4 = (const float4*)xs;
  const int base4 = row * 32 + q * 2;
  short8 afr[4];
  #pragma unroll
  for (int kkk = 0; kkk < 4; ++kkk) {
    float4 f0 = xs4[base4 + kkk * 8];
    float4 f1 = xs4[base4 + kkk * 8 + 1];
    union { short8 s; uint4 u; } a;
    a.u.x = f2bf(f0.x) | (f2bf(f0.y) << 16);
    a.u.y = f2bf(f0.z) | (f2bf(f0.w) << 16);
    a.u.z = f2bf(f1.x) | (f2bf(f1.y) << 16);
    a.u.w = f2bf(f1.z) | (f2bf(f1.w) << 16);
    afr[kkk] = a.s;
  }

  // prefetch first cg (ci0 = ch*16) into buf0: 2 units/thread
  const int ci0 = ch * 16;
  uint4 v[2];
  #pragma unroll
  for (int i = 0; i < 2; ++i) {
    const int u = i * 256 + t;
    v[i] = musbf_sw[((ci0 >> 1) << 10) + ((u >> 5) << 6) + ((ci0 & 1) << 5) + (u & 31)];
  }
  #pragma unroll
  for (int i = 0; i < 2; ++i) *(uint4*)&Bs[0][(i * 256 + t) * 8] = v[i];
  __syncthreads();

  // packed constants (register pairs, loop-invariant)
  const f32x2 C_mh = {-0.5f, -0.5f}, C_ph = {0.5f, 0.5f};
  const f32x2 C_z0 = {0.0f, 0.0f};
  const f32x2 C5 = {-3.6067376f, -3.6067376f};
  const f32x2 C4 = {-2.3449500f, -2.3449500f};
  const f32x2 C3 = {-3.2975886f, -3.2975886f};
  const f32x2 C2 = {-5.1295823f, -5.1295823f};
  const f32x2 C1 = {-9.6179669f, -9.6179669f};
  const f32x2 C0 = {-28.8539008f, -28.8539008f};

  f32x2 sums2[2] = {(f32x2){0.f, 0.f}, (f32x2){0.f, 0.f}};   // rows (0,1),(2,3)

  for (int cgi = 0; cgi < 16; ++cgi) {
    const int ci = ci0 + cgi;
    if (cgi < 15) {                       // issue next-B loads (overlap compute)
      const int cn = ci + 1;
      #pragma unroll
      for (int i = 0; i < 2; ++i) {
        const int u = i * 256 + t;
        v[i] = musbf_sw[((cn >> 1) << 10) + ((u >> 5) << 6) + ((cn & 1) << 5) + (u & 31)];
      }
    }
    float lwv[2];
    #pragma unroll
    for (int nt = 0; nt < 2; ++nt) lwv[nt] = lw[ci * 32 + nt * 16 + l15];

    f32x4 acc[2];
    #pragma unroll
    for (int nt = 0; nt < 2; ++nt) acc[nt] = (f32x4){0.f, 0.f, 0.f, 0.f};
    const unsigned short* bp = &Bs[cgi & 1][q * 256 + l15 * 8];
    #pragma unroll
    for (int kkk = 0; kkk < 4; ++kkk)
      #pragma unroll
      for (int nt = 0; nt < 2; ++nt) {
        short8 b = *(const short8*)(bp + kkk * 1024 + nt * 128);
        acc[nt] = __builtin_amdgcn_mfma_f32_16x16x32_bf16(afr[kkk], b, acc[nt], 0, 0, 0);
      }

    // packed epilogue: term = exp2(z*H(z) + lw), z=(1-x)/2
    #pragma unroll
    for (int nt = 0; nt < 2; ++nt) {
      f32x2 lwp = {lwv[nt], lwv[nt]};
      #pragma unroll
      for (int p = 0; p < 2; ++p) {
        f32x2 x = {acc[nt][2 * p], acc[nt][2 * p + 1]};
        f32x2 z = pk_fma(x, C_mh, C_ph);
        z = __builtin_elementwise_max(z, C_z0);
        f32x2 h = pk_fma(z, C5, C4);
        h = pk_fma(z, h, C3);
        h = pk_fma(z, h, C2);
        h = pk_fma(z, h, C1);
        h = pk_fma(z, h, C0);
        f32x2 arg = pk_fma(z, h, lwp);
        f32x2 e = {__builtin_amdgcn_exp2f(arg.x), __builtin_amdgcn_exp2f(arg.y)};
        sums2[p] = sums2[p] + e;
      }
    }

    if (cgi < 15) {                       // commit prefetch to other buffer
      #pragma unroll
      for (int i = 0; i < 2; ++i)
        *(uint4*)&Bs[(cgi + 1) & 1][(i * 256 + t) * 8] = v[i];
      __syncthreads();
    }
  }

  // reduce over the 16 col-lanes; rows = q*4+r; combine col halves atomically
  float s[4] = {sums2[0].x, sums2[0].y, sums2[1].x, sums2[1].y};
  #pragma unroll
  for (int s2 = 1; s2 < 16; s2 <<= 1)
    #pragma unroll
    for (int r = 0; r < 4; ++r) s[r] += __shfl_xor(s[r], s2, 64);
  if (l15 == 0) {
    #pragma unroll
    for (int r = 0; r < 4; ++r)
      atomicAdd(&out[rblk * 64 + wv * 16 + q * 4 + r], s[r]);
  }
}

// ---- fin: out[i] = 0.1*log1p(1/S) in place (stream-ordered after main).
__global__ __launch_bounds__(256) void fin_kernel(float* __restrict__ out) {
  const int i = blockIdx.x * 256 + threadIdx.x;
  float S = out[i];
  out[i] = 0.1f * log1pf(1.0f / S);
}

extern "C" void kernel_launch(void* const* d_in, const int* in_sizes, int n_in,
                              void* d_out, int out_size, void* d_ws, size_t ws_size,
                              hipStream_t stream) {
  const float* xs     = (const float*)d_in[0];   // [65536,128]
  const float* mus    = (const float*)d_in[1];   // [128,1024]
  const float* alphas = (const float*)d_in[2];   // [1024]
  float* out = (float*)d_out;

  uint4* musbf_sw = (uint4*)d_ws;                              // 256 KiB
  float* lw = (float*)((char*)d_ws + 16384 * sizeof(uint4));   // 4 KiB

  // self-sufficient zero of the atomic accumulator (stream-ordered,
  // graph-capture-safe; do not rely on harness re-poison semantics)
  hipMemsetAsync(out, 0, (size_t)out_size * sizeof(float), stream);

  prep_kernel<<<KP / 16, 256, 0, stream>>>(mus, alphas, musbf_sw, lw);
  const int B = in_sizes[0] / DD;   // 65536
  main_kernel<<<B / 32, 256, 0, stream>>>(xs, musbf_sw, lw, out);
  fin_kernel<<<B / 256, 256, 0, stream>>>(out);
}